// Round 2
// baseline (705.998 us; speedup 1.0000x reference)
//
#include <hip/hip_runtime.h>
#include <math.h>

typedef _Float16 f16;
typedef _Float16 half8 __attribute__((ext_vector_type(8)));
typedef float floatx4 __attribute__((ext_vector_type(4)));

// ---------------- ws layout (bytes) ----------------
// [0, 94208)             f16 weights, padded+transposed+bank-swizzled (47104 elems)
//   L0: [64][32]  @0      L1: [112][64] @2048   L2: [112][128] @9216
//   L3: [112][128]@23552  L4: [64][128] @37888  L5: [16][64]   @46080
// [94208, 96128)         f32 biases, zero-padded to Np per layer (480 floats)
// [96128, 96128+16B)     f16 invariants [B][8] (5 used, 3 zero)
// [.., +40B)             f32 g [B][10]

__device__ __forceinline__ void mm3(const float* A, const float* Bm, float* C) {
  #pragma unroll
  for (int i = 0; i < 3; ++i)
    #pragma unroll
    for (int j = 0; j < 3; ++j)
      C[i*3+j] = A[i*3]*Bm[j] + A[i*3+1]*Bm[3+j] + A[i*3+2]*Bm[6+j];
}

// ---------------- k0: weight/bias prep ----------------
__global__ void k0_prep(const float* W0, const float* B0, const float* W1, const float* B1,
                        const float* W2, const float* B2, const float* W3, const float* B3,
                        const float* W4, const float* B4, const float* W5, const float* B5,
                        f16* wt, float* biasp) {
  int idx = blockIdx.x * 256 + threadIdx.x;
  if (idx < 47104) {
    const float* W; int K, N, sh, loc;
    if (idx < 2048)       { W = W0; K = 5;   N = 50;  sh = 5; loc = idx; }
    else if (idx < 9216)  { W = W1; K = 50;  N = 100; sh = 6; loc = idx - 2048; }
    else if (idx < 23552) { W = W2; K = 100; N = 100; sh = 7; loc = idx - 9216; }
    else if (idx < 37888) { W = W3; K = 100; N = 100; sh = 7; loc = idx - 23552; }
    else if (idx < 46080) { W = W4; K = 100; N = 50;  sh = 7; loc = idx - 37888; }
    else                  { W = W5; K = 50;  N = 10;  sh = 6; loc = idx - 46080; }
    int Kp  = 1 << sh;
    int n   = loc >> sh;
    int kp  = loc & (Kp - 1);
    int chm = (Kp >> 3) - 1;                                   // chunk swizzle mask
    int klog = (((kp >> 3) ^ (n & chm)) << 3) | (kp & 7);      // XOR swizzle (involution)
    float v = (n < N && klog < K) ? W[klog * N + n] : 0.f;     // transpose: Wt[n][k] = W[k][n]
    wt[idx] = (f16)v;
  }
  int bi = idx - 47104;
  if (bi >= 0 && bi < 480) {
    const float* Bv; int N, loc;
    if (bi < 64)       { Bv = B0; N = 50;  loc = bi; }
    else if (bi < 176) { Bv = B1; N = 100; loc = bi - 64; }
    else if (bi < 288) { Bv = B2; N = 100; loc = bi - 176; }
    else if (bi < 400) { Bv = B3; N = 100; loc = bi - 288; }
    else if (bi < 464) { Bv = B4; N = 50;  loc = bi - 400; }
    else               { Bv = B5; N = 10;  loc = bi - 464; }
    biasp[bi] = (loc < N) ? Bv[loc] : 0.f;
  }
}

// ---------------- k1: invariants (fp32 compute, f16 store) ----------------
__global__ void k1_inv(const float* __restrict__ s, const float* __restrict__ w,
                       f16* __restrict__ inv, int B) {
  int b = blockIdx.x * 256 + threadIdx.x;
  if (b >= B) return;
  float S[9], W[9];
  #pragma unroll
  for (int i = 0; i < 9; ++i) { S[i] = s[(size_t)b*9 + i]; W[i] = w[(size_t)b*9 + i]; }
  float S2[9], W2[9];
  mm3(S, S, S2); mm3(W, W, W2);
  float lam1 = S2[0] + S2[4] + S2[8];
  float lam2 = W2[0] + W2[4] + W2[8];
  float lam3 = 0.f, lam4 = 0.f, lam5 = 0.f;
  #pragma unroll
  for (int i = 0; i < 3; ++i)
    #pragma unroll
    for (int j = 0; j < 3; ++j) {
      float sji = S[j*3 + i];
      lam3 += S2[i*3 + j] * sji;
      lam4 += W2[i*3 + j] * sji;
      lam5 += W2[i*3 + j] * S2[j*3 + i];
    }
  union { f16 h[8]; int4 v; } u;
  u.h[0] = (f16)lam1; u.h[1] = (f16)lam2; u.h[2] = (f16)lam3;
  u.h[3] = (f16)lam4; u.h[4] = (f16)lam5;
  u.h[5] = (f16)0.f;  u.h[6] = (f16)0.f; u.h[7] = (f16)0.f;
  *(int4*)(inv + (size_t)b * 8) = u.v;
}

// ---------------- k2: fused 6-layer MLP via f16 MFMA ----------------
// Block = 256 thr = 4 waves, 64 batch rows/block. Transposed GEMM: y^T = Wt @ x^T
//   A-frag (Wt):  row n = nt*16 + (lane&15), k = kt*32 + quad*8 + j   (ds_read_b128)
//   B-frag (x):   row m = rt*16 + (lane&15), k = kt*32 + quad*8 + j   (ds_read_b128)
//   D:            n = quad*4 + reg (4 consecutive neurons!), m = lane&15 -> b64 y-write
// LDS swizzle: chunk' = chunk ^ (row & (CH-1)) keeps frag accesses <=2-way (free).
// NOTE (R1 fix): lds_x is zero-initialized at block start. NP=112 layers only
// write logical chunks 0..13, but KP=128 consumers read chunks 0..15; garbage
// LDS there (possible NaN bit patterns) gave 0*NaN=NaN inside MFMA.
template<int KP, int NP, int WOFF, int BOFF, int LIDX>
__device__ __forceinline__ void mlp_layer(
    const f16* __restrict__ wt, const float* __restrict__ biasp,
    const f16* __restrict__ inv, float* __restrict__ g,
    f16* lds_wts, const f16* xsrc, f16* ydst,
    int tid, int B, int blockRow) {
  const int lane = tid & 63;
  const int wv   = tid >> 6;
  const int mh   = lane & 15;
  const int q    = lane >> 4;

  __syncthreads();   // prior layer's LDS reads done before overwriting wts / reading y
  {
    const int cnt = NP * KP / 8;                 // int4 chunks
    const int4* src = (const int4*)(wt + WOFF);
    int4* dst = (int4*)lds_wts;
    #pragma unroll 1
    for (int i = tid; i < cnt; i += 256) dst[i] = src[i];
  }
  __syncthreads();

  constexpr int NT = NP / 16;
  int nt0, ntc;
  if constexpr (NT == 7)      { nt0 = wv; ntc = (wv < 3) ? 2 : 1; }  // tiles {wv, wv+4}
  else if constexpr (NT == 4) { nt0 = wv; ntc = 1; }
  else                        { nt0 = 0;  ntc = (wv == 0) ? 1 : 0; } // NT==1 (final)

  floatx4 C[2][4];
  #pragma unroll
  for (int i = 0; i < 2; ++i)
    #pragma unroll
    for (int r = 0; r < 4; ++r) C[i][r] = (floatx4){0.f, 0.f, 0.f, 0.f};

  constexpr int KT = KP / 32;
  #pragma unroll
  for (int kt = 0; kt < KT; ++kt) {
    half8 A[2], Bf[4];
    #pragma unroll
    for (int i = 0; i < 2; ++i) {
      A[i] = (half8)(f16)0.f;
      if (i < ntc) {
        int n   = (nt0 + i*4) * 16 + mh;
        int cph = (kt*4 + q) ^ (n & ((KP >> 3) - 1));
        A[i] = *(const half8*)(lds_wts + n*KP + cph*8);
      }
    }
    #pragma unroll
    for (int r = 0; r < 4; ++r) {
      if constexpr (LIDX == 0) {
        int row = blockRow + r*16 + mh;
        half8 z = {(f16)0.f,(f16)0.f,(f16)0.f,(f16)0.f,(f16)0.f,(f16)0.f,(f16)0.f,(f16)0.f};
        if (q == 0 && row < B) z = *(const half8*)(inv + (size_t)row * 8);
        Bf[r] = z;                                   // K=5 padded to 32: quads 1-3 are zero
      } else {
        int row = r*16 + mh;
        int cph = (kt*4 + q) ^ mh;
        Bf[r] = *(const half8*)(xsrc + row*128 + cph*8);
      }
    }
    #pragma unroll
    for (int i = 0; i < 2; ++i) {
      if (i < ntc) {
        #pragma unroll
        for (int r = 0; r < 4; ++r)
          C[i][r] = __builtin_amdgcn_mfma_f32_16x16x32_f16(A[i], Bf[r], C[i][r], 0, 0, 0);
      }
    }
  }

  #pragma unroll
  for (int i = 0; i < 2; ++i) {
    if (i < ntc) {
      int nt = nt0 + i*4;
      if constexpr (LIDX < 5) {
        floatx4 bia = *(const floatx4*)(biasp + BOFF + nt*16 + q*4);
        #pragma unroll
        for (int r = 0; r < 4; ++r) {
          union { f16 h[4]; uint2 u; } pk;
          #pragma unroll
          for (int e = 0; e < 4; ++e) {
            float v = C[i][r][e] + bia[e];
            v = (v > 0.f) ? v : 0.1f * v;            // leaky_relu(0.1)
            pk.h[e] = (f16)v;
          }
          int row = r*16 + mh;                        // batch row (lane&15!)
          int cph = (nt*2 + (q >> 1)) ^ mh;           // swizzled chunk of col = nt*16+q*4
          *(uint2*)(ydst + row*128 + cph*8 + (q & 1)*4) = pk.u;  // 4 consecutive neurons
        }
      } else {
        floatx4 bia = *(const floatx4*)(biasp + BOFF + q*4);
        #pragma unroll
        for (int r = 0; r < 4; ++r) {
          int grow = blockRow + r*16 + mh;
          if (grow < B) {
            #pragma unroll
            for (int e = 0; e < 4; ++e) {
              int n = q*4 + e;
              if (n < 10) g[(size_t)grow*10 + n] = C[i][r][e] + bia[e];  // final: linear
            }
          }
        }
      }
    }
  }
}

__global__ __launch_bounds__(256, 2) void k2_mlp(const f16* __restrict__ wt,
    const float* __restrict__ biasp, const f16* __restrict__ inv,
    float* __restrict__ g, int B) {
  __shared__ __align__(16) f16 lds_wts[112*128];     // 28672 B (max layer)
  __shared__ __align__(16) f16 lds_x[2][64*128];     // 2 x 16384 B ping-pong; total LDS 61440 B
  int tid = threadIdx.x;
  int blockRow = blockIdx.x * 64;

  // R1 fix: zero both activation buffers (2*64*128 f16 = 2048 int4).
  // Ordered before any reader by layer 0's top __syncthreads().
  {
    int4* p = (int4*)&lds_x[0][0];
    int4 z; z.x = 0; z.y = 0; z.z = 0; z.w = 0;
    #pragma unroll 1
    for (int i = tid; i < 2048; i += 256) p[i] = z;
  }

  mlp_layer< 32,  64,     0,   0, 0>(wt, biasp, inv, g, lds_wts, (const f16*)nullptr, lds_x[0], tid, B, blockRow);
  mlp_layer< 64, 112,  2048,  64, 1>(wt, biasp, inv, g, lds_wts, lds_x[0], lds_x[1], tid, B, blockRow);
  mlp_layer<128, 112,  9216, 176, 2>(wt, biasp, inv, g, lds_wts, lds_x[1], lds_x[0], tid, B, blockRow);
  mlp_layer<128, 112, 23552, 288, 3>(wt, biasp, inv, g, lds_wts, lds_x[0], lds_x[1], tid, B, blockRow);
  mlp_layer<128,  64, 37888, 400, 4>(wt, biasp, inv, g, lds_wts, lds_x[1], lds_x[0], tid, B, blockRow);
  mlp_layer< 64,  16, 46080, 464, 5>(wt, biasp, inv, g, lds_wts, lds_x[0], lds_x[1], tid, B, blockRow);
}

// ---------------- k3: tensor bases + contraction + normalize (fp32) ----------------
__global__ void k3_final(const float* __restrict__ s, const float* __restrict__ w,
                         const float* __restrict__ g, float* __restrict__ out, int B) {
  int b = blockIdx.x * 256 + threadIdx.x;
  if (b >= B) return;
  float S[9], W[9], G[10];
  #pragma unroll
  for (int i = 0; i < 9; ++i) { S[i] = s[(size_t)b*9 + i]; W[i] = w[(size_t)b*9 + i]; }
  #pragma unroll
  for (int i = 0; i < 10; ++i) G[i] = g[(size_t)b*10 + i];

  float S2[9], W2[9], SW[9], WS[9];
  mm3(S,S,S2); mm3(W,W,W2); mm3(S,W,SW); mm3(W,S,WS);
  float WS2[9], S2W[9], W2S[9], SW2[9], S2W2[9], W2S2[9];
  mm3(W,S2,WS2); mm3(S2,W,S2W); mm3(W2,S,W2S); mm3(S,W2,SW2);
  mm3(S2,W2,S2W2); mm3(W2,S2,W2S2);

  float lam1 = S2[0]+S2[4]+S2[8];
  float lam2 = W2[0]+W2[4]+W2[8];
  float tr6  = SW2[0]+SW2[4]+SW2[8];
  float tr9  = S2W2[0]+S2W2[4]+S2W2[8];

  float Q[9];
  #pragma unroll
  for (int i = 0; i < 9; ++i)
    Q[i] = G[0]*S[i] + G[1]*(SW[i]-WS[i]) + G[2]*S2[i] + G[3]*W2[i]
         + G[4]*(WS2[i]-S2W[i]) + G[5]*(W2S[i]+SW2[i]) + G[8]*(W2S2[i]+S2W2[i]);

  float TA[9], TB[9];
  mm3(WS,W2,TA);  mm3(W2,SW,TB);     // T7
  #pragma unroll
  for (int i = 0; i < 9; ++i) Q[i] += G[6]*(TA[i]-TB[i]);
  mm3(SW,S2,TA);  mm3(S2,WS,TB);     // T8
  #pragma unroll
  for (int i = 0; i < 9; ++i) Q[i] += G[7]*(TA[i]-TB[i]);
  mm3(WS2,W2,TA); mm3(W2,S2W,TB);    // T10
  #pragma unroll
  for (int i = 0; i < 9; ++i) Q[i] += G[9]*(TA[i]-TB[i]);

  float diag = G[2]*lam1*(1.f/3.f) + G[3]*lam2*(1.f/3.f)
             + G[5]*(2.f/3.f)*tr6 + G[8]*(2.f/3.f)*tr9;
  Q[0] -= diag; Q[4] -= diag; Q[8] -= diag;

  // output 1: raw
  #pragma unroll
  for (int i = 0; i < 9; ++i) out[(size_t)9*B + (size_t)b*9 + i] = Q[i];

  // output 0: deviatoric, symmetrized, normalized
  float t3 = (Q[0]+Q[4]+Q[8]) * (1.f/3.f);
  Q[0] -= t3; Q[4] -= t3; Q[8] -= t3;
  float Qs[9];
  #pragma unroll
  for (int i = 0; i < 3; ++i)
    #pragma unroll
    for (int j = 0; j < 3; ++j) Qs[i*3+j] = 0.5f*(Q[i*3+j] + Q[j*3+i]);
  float ns = 0.f;
  #pragma unroll
  for (int i = 0; i < 9; ++i) ns += Qs[i]*Qs[i];
  float rinv = 1.f / sqrtf(ns + 1e-16f);
  #pragma unroll
  for (int i = 0; i < 9; ++i) out[(size_t)b*9 + i] = Qs[i]*rinv;
}

// ---------------- launcher ----------------
extern "C" void kernel_launch(void* const* d_in, const int* in_sizes, int n_in,
                              void* d_out, int out_size, void* d_ws, size_t ws_size,
                              hipStream_t stream) {
  const float* s = (const float*)d_in[0];
  const float* w = (const float*)d_in[1];
  const int B = in_sizes[0] / 9;
  char* ws = (char*)d_ws;
  f16*   wt    = (f16*)ws;
  float* biasp = (float*)(ws + 94208);
  f16*   inv   = (f16*)(ws + 96128);
  float* g     = (float*)(ws + 96128 + (size_t)B * 16);
  float* out   = (float*)d_out;

  k0_prep<<<dim3(186), dim3(256), 0, stream>>>(
      (const float*)d_in[2],  (const float*)d_in[3],  (const float*)d_in[4],  (const float*)d_in[5],
      (const float*)d_in[6],  (const float*)d_in[7],  (const float*)d_in[8],  (const float*)d_in[9],
      (const float*)d_in[10], (const float*)d_in[11], (const float*)d_in[12], (const float*)d_in[13],
      wt, biasp);
  k1_inv<<<dim3((B + 255) / 256), dim3(256), 0, stream>>>(s, w, inv, B);
  k2_mlp<<<dim3((B + 63) / 64),   dim3(256), 0, stream>>>(wt, biasp, inv, g, B);
  k3_final<<<dim3((B + 255) / 256), dim3(256), 0, stream>>>(s, w, g, out, B);
}

// Round 6
// 472.168 us; speedup vs baseline: 1.4952x; 1.4952x over previous
//
#include <hip/hip_runtime.h>
#include <math.h>

typedef _Float16 f16;
typedef _Float16 half8 __attribute__((ext_vector_type(8)));
typedef float floatx4 __attribute__((ext_vector_type(4)));

// ---------------- ws layout (bytes) ----------------
// [0, 94208)       f16 weights, padded+transposed+bank-swizzled (R2 k0, verbatim)
//   L0: [64][32]  @0      L1: [112][64] @2048   L2: [112][128] @9216
//   L3: [112][128]@23552  L4: [64][128] @37888  L5: [16][64]   @46080
// [94208, 96128)   f32 biases, zero-padded to Np per layer (480 floats)

__device__ __forceinline__ void mm3(const float* A, const float* Bm, float* C) {
  #pragma unroll
  for (int i = 0; i < 3; ++i)
    #pragma unroll
    for (int j = 0; j < 3; ++j)
      C[i*3+j] = A[i*3]*Bm[j] + A[i*3+1]*Bm[3+j] + A[i*3+2]*Bm[6+j];
}

// ---------------- k0: weight/bias prep (R2-passing version, verbatim) -------
__global__ void k0_prep(const float* W0, const float* B0, const float* W1, const float* B1,
                        const float* W2, const float* B2, const float* W3, const float* B3,
                        const float* W4, const float* B4, const float* W5, const float* B5,
                        f16* wt, float* biasp) {
  int idx = blockIdx.x * 256 + threadIdx.x;
  if (idx < 47104) {
    const float* W; int K, N, sh, loc;
    if (idx < 2048)       { W = W0; K = 5;   N = 50;  sh = 5; loc = idx; }
    else if (idx < 9216)  { W = W1; K = 50;  N = 100; sh = 6; loc = idx - 2048; }
    else if (idx < 23552) { W = W2; K = 100; N = 100; sh = 7; loc = idx - 9216; }
    else if (idx < 37888) { W = W3; K = 100; N = 100; sh = 7; loc = idx - 23552; }
    else if (idx < 46080) { W = W4; K = 100; N = 50;  sh = 7; loc = idx - 37888; }
    else                  { W = W5; K = 50;  N = 10;  sh = 6; loc = idx - 46080; }
    int Kp  = 1 << sh;
    int n   = loc >> sh;
    int kp  = loc & (Kp - 1);
    int chm = (Kp >> 3) - 1;                                   // chunk swizzle mask
    int klog = (((kp >> 3) ^ (n & chm)) << 3) | (kp & 7);      // XOR swizzle (involution)
    float v = (n < N && klog < K) ? W[klog * N + n] : 0.f;     // transpose: Wt[n][k] = W[k][n]
    wt[idx] = (f16)v;
  }
  int bi = idx - 47104;
  if (bi >= 0 && bi < 480) {
    const float* Bv; int N, loc;
    if (bi < 64)       { Bv = B0; N = 50;  loc = bi; }
    else if (bi < 176) { Bv = B1; N = 100; loc = bi - 64; }
    else if (bi < 288) { Bv = B2; N = 100; loc = bi - 176; }
    else if (bi < 400) { Bv = B3; N = 100; loc = bi - 288; }
    else if (bi < 464) { Bv = B4; N = 50;  loc = bi - 400; }
    else               { Bv = B5; N = 10;  loc = bi - 464; }
    biasp[bi] = (loc < N) ? Bv[loc] : 0.f;
  }
}

// ---------------- MLP layer: R2-passing k2 structure, verbatim --------------
// Block = 256 thr = 4 waves, 64 batch rows/block. Transposed GEMM: y^T = Wt @ x^T
//   A-frag (Wt):  row n = nt*16 + (lane&15), k = kt*32 + quad*8 + j   (ds_read_b128)
//   B-frag (x):   row m = rt*16 + (lane&15), k = kt*32 + quad*8 + j   (ds_read_b128)
//   D:            n = quad*4 + reg (4 consecutive neurons), m = lane&15
// LDS swizzle: chunk' = chunk ^ (row & (CH-1)).
// Changes vs R2 (edges only): layer 0 reads invariants from LDS linv (same
// [row][8] f16 format R2 read from global); layer 5 writes g to LDS gLDS
// (same scalar n<10-guarded stores R2 made to global g). All GEMM indexing,
// staging, barriers, and accumulation order are bit-identical to R2.
template<int KP, int NP, int WOFF, int BOFF, int LIDX>
__device__ __forceinline__ void mlp_layer(
    const f16* __restrict__ wt, const float* __restrict__ biasp,
    const f16* linv, float* gLDS,
    f16* lds_wts, const f16* xsrc, f16* ydst, int tid) {
  const int lane = tid & 63;
  const int wv   = tid >> 6;
  const int mh   = lane & 15;
  const int q    = lane >> 4;

  __syncthreads();   // prior layer's LDS reads done before overwriting wts
  {
    const int cnt = NP * KP / 8;                 // int4 chunks
    const int4* src = (const int4*)(wt + WOFF);
    int4* dst = (int4*)lds_wts;
    #pragma unroll 1
    for (int i = tid; i < cnt; i += 256) dst[i] = src[i];
  }
  __syncthreads();

  constexpr int NT = NP / 16;
  int nt0, ntc;
  if constexpr (NT == 7)      { nt0 = wv; ntc = (wv < 3) ? 2 : 1; }  // tiles {wv, wv+4}
  else if constexpr (NT == 4) { nt0 = wv; ntc = 1; }
  else                        { nt0 = 0;  ntc = (wv == 0) ? 1 : 0; } // NT==1 (final)

  floatx4 C[2][4];
  #pragma unroll
  for (int i = 0; i < 2; ++i)
    #pragma unroll
    for (int r = 0; r < 4; ++r) C[i][r] = (floatx4){0.f, 0.f, 0.f, 0.f};

  constexpr int KT = KP / 32;
  #pragma unroll
  for (int kt = 0; kt < KT; ++kt) {
    half8 A[2], Bf[4];
    #pragma unroll
    for (int i = 0; i < 2; ++i) {
      A[i] = (half8)(f16)0.f;
      if (i < ntc) {
        int n   = (nt0 + i*4) * 16 + mh;
        int cph = (kt*4 + q) ^ (n & ((KP >> 3) - 1));
        A[i] = *(const half8*)(lds_wts + n*KP + cph*8);
      }
    }
    #pragma unroll
    for (int r = 0; r < 4; ++r) {
      if constexpr (LIDX == 0) {
        half8 z = {(f16)0.f,(f16)0.f,(f16)0.f,(f16)0.f,(f16)0.f,(f16)0.f,(f16)0.f,(f16)0.f};
        if (q == 0) z = *(const half8*)(linv + (r*16 + mh)*8);
        Bf[r] = z;                                   // K=5 padded to 32: quads 1-3 zero
      } else {
        int row = r*16 + mh;
        int cph = (kt*4 + q) ^ mh;
        Bf[r] = *(const half8*)(xsrc + row*128 + cph*8);
      }
    }
    #pragma unroll
    for (int i = 0; i < 2; ++i) {
      if (i < ntc) {
        #pragma unroll
        for (int r = 0; r < 4; ++r)
          C[i][r] = __builtin_amdgcn_mfma_f32_16x16x32_f16(A[i], Bf[r], C[i][r], 0, 0, 0);
      }
    }
  }

  #pragma unroll
  for (int i = 0; i < 2; ++i) {
    if (i < ntc) {
      int nt = nt0 + i*4;
      if constexpr (LIDX < 5) {
        floatx4 bia = *(const floatx4*)(biasp + BOFF + nt*16 + q*4);
        #pragma unroll
        for (int r = 0; r < 4; ++r) {
          union { f16 h[4]; uint2 u; } pk;
          #pragma unroll
          for (int e = 0; e < 4; ++e) {
            float v = C[i][r][e] + bia[e];
            v = (v > 0.f) ? v : 0.1f * v;            // leaky_relu(0.1)
            pk.h[e] = (f16)v;
          }
          int row = r*16 + mh;                        // batch row (lane&15)
          int cph = (nt*2 + (q >> 1)) ^ mh;           // swizzled chunk of col nt*16+q*4
          *(uint2*)(ydst + row*128 + cph*8 + (q & 1)*4) = pk.u;
        }
      } else {
        floatx4 bia = *(const floatx4*)(biasp + BOFF + q*4);
        #pragma unroll
        for (int r = 0; r < 4; ++r) {
          int slot = r*16 + mh;
          #pragma unroll
          for (int e = 0; e < 4; ++e) {
            int n = q*4 + e;
            if (n < 10) gLDS[slot*10 + n] = C[i][r][e] + bia[e];   // final: linear
          }
        }
      }
    }
  }
}

// ---------------- fused kernel: invariants -> MLP (R2 core) -> bases --------
__global__ __launch_bounds__(256, 2) void k_fused(
    const f16* __restrict__ wt, const float* __restrict__ biasp,
    const float* __restrict__ s, const float* __restrict__ w,
    float* __restrict__ out, int B) {
  __shared__ __align__(16) f16 lds_wts[112*128];     // 28672 B (max layer)
  __shared__ __align__(16) f16 lds_x[2][64*128];     // 2 x 16384 B ping-pong
  __shared__ __align__(16) f16 linv[64*8];           // 1024 B invariants
  __shared__ __align__(16) float gLDS[64*10];        // 2560 B g
  int tid = threadIdx.x;
  int blockRow = blockIdx.x * 64;

  // zero both activation buffers (padding chunks must be exact zero; R1 fix)
  {
    int4* p = (int4*)&lds_x[0][0];
    int4 z; z.x = 0; z.y = 0; z.z = 0; z.w = 0;
    #pragma unroll 1
    for (int i = tid; i < 2048; i += 256) p[i] = z;
  }

  // ---- phase A: invariants (k1 body verbatim), rows blockRow..+63 ----
  if (tid < 64) {
    int row = blockRow + tid;
    union { f16 h[8]; int4 v; } u;
    u.v.x = 0; u.v.y = 0; u.v.z = 0; u.v.w = 0;
    if (row < B) {
      float S[9], W[9];
      #pragma unroll
      for (int i = 0; i < 9; ++i) { S[i] = s[(size_t)row*9 + i]; W[i] = w[(size_t)row*9 + i]; }
      float S2[9], W2[9];
      mm3(S, S, S2); mm3(W, W, W2);
      float lam1 = S2[0] + S2[4] + S2[8];
      float lam2 = W2[0] + W2[4] + W2[8];
      float lam3 = 0.f, lam4 = 0.f, lam5 = 0.f;
      #pragma unroll
      for (int i = 0; i < 3; ++i)
        #pragma unroll
        for (int j = 0; j < 3; ++j) {
          float sji = S[j*3 + i];
          lam3 += S2[i*3 + j] * sji;
          lam4 += W2[i*3 + j] * sji;
          lam5 += W2[i*3 + j] * S2[j*3 + i];
        }
      u.h[0] = (f16)lam1; u.h[1] = (f16)lam2; u.h[2] = (f16)lam3;
      u.h[3] = (f16)lam4; u.h[4] = (f16)lam5;
    }
    *(int4*)(linv + tid*8) = u.v;
  }
  // ordering: phase A / zero-init precede layer 0's internal __syncthreads

  // ---- phase B: 6 MFMA layers (R2 k2 core) ----
  mlp_layer< 32,  64,     0,   0, 0>(wt, biasp, linv, gLDS, lds_wts, (const f16*)nullptr, lds_x[0], tid);
  mlp_layer< 64, 112,  2048,  64, 1>(wt, biasp, linv, gLDS, lds_wts, lds_x[0], lds_x[1], tid);
  mlp_layer<128, 112,  9216, 176, 2>(wt, biasp, linv, gLDS, lds_wts, lds_x[1], lds_x[0], tid);
  mlp_layer<128, 112, 23552, 288, 3>(wt, biasp, linv, gLDS, lds_wts, lds_x[0], lds_x[1], tid);
  mlp_layer<128,  64, 37888, 400, 4>(wt, biasp, linv, gLDS, lds_wts, lds_x[1], lds_x[0], tid);
  mlp_layer< 64,  16, 46080, 464, 5>(wt, biasp, linv, gLDS, lds_wts, lds_x[0], lds_x[1], tid);

  __syncthreads();   // gLDS (written by wave 0) visible to phase C

  // ---- phase C: tensor bases + contraction + normalize (k3 body verbatim) ----
  if (tid < 64) {
    int row = blockRow + tid;
    if (row < B) {
      float G[10];
      #pragma unroll
      for (int i = 0; i < 10; ++i) G[i] = gLDS[tid*10 + i];
      float S[9], W[9];
      #pragma unroll
      for (int i = 0; i < 9; ++i) { S[i] = s[(size_t)row*9 + i]; W[i] = w[(size_t)row*9 + i]; }

      float S2[9], W2[9], SW[9], WS[9];
      mm3(S,S,S2); mm3(W,W,W2); mm3(S,W,SW); mm3(W,S,WS);
      float WS2[9], S2W[9], W2S[9], SW2[9], S2W2[9], W2S2[9];
      mm3(W,S2,WS2); mm3(S2,W,S2W); mm3(W2,S,W2S); mm3(S,W2,SW2);
      mm3(S2,W2,S2W2); mm3(W2,S2,W2S2);

      float lam1 = S2[0]+S2[4]+S2[8];
      float lam2 = W2[0]+W2[4]+W2[8];
      float tr6  = SW2[0]+SW2[4]+SW2[8];
      float tr9  = S2W2[0]+S2W2[4]+S2W2[8];

      float Q[9];
      #pragma unroll
      for (int i = 0; i < 9; ++i)
        Q[i] = G[0]*S[i] + G[1]*(SW[i]-WS[i]) + G[2]*S2[i] + G[3]*W2[i]
             + G[4]*(WS2[i]-S2W[i]) + G[5]*(W2S[i]+SW2[i]) + G[8]*(W2S2[i]+S2W2[i]);

      float TA[9], TB[9];
      mm3(WS,W2,TA);  mm3(W2,SW,TB);     // T7
      #pragma unroll
      for (int i = 0; i < 9; ++i) Q[i] += G[6]*(TA[i]-TB[i]);
      mm3(SW,S2,TA);  mm3(S2,WS,TB);     // T8
      #pragma unroll
      for (int i = 0; i < 9; ++i) Q[i] += G[7]*(TA[i]-TB[i]);
      mm3(WS2,W2,TA); mm3(W2,S2W,TB);    // T10
      #pragma unroll
      for (int i = 0; i < 9; ++i) Q[i] += G[9]*(TA[i]-TB[i]);

      float diag = G[2]*lam1*(1.f/3.f) + G[3]*lam2*(1.f/3.f)
                 + G[5]*(2.f/3.f)*tr6 + G[8]*(2.f/3.f)*tr9;
      Q[0] -= diag; Q[4] -= diag; Q[8] -= diag;

      // output 1: raw
      #pragma unroll
      for (int i = 0; i < 9; ++i) out[(size_t)9*B + (size_t)row*9 + i] = Q[i];

      // output 0: deviatoric, symmetrized, normalized
      float t3 = (Q[0]+Q[4]+Q[8]) * (1.f/3.f);
      Q[0] -= t3; Q[4] -= t3; Q[8] -= t3;
      float Qs[9];
      #pragma unroll
      for (int i = 0; i < 3; ++i)
        #pragma unroll
        for (int j = 0; j < 3; ++j) Qs[i*3+j] = 0.5f*(Q[i*3+j] + Q[j*3+i]);
      float ns = 0.f;
      #pragma unroll
      for (int i = 0; i < 9; ++i) ns += Qs[i]*Qs[i];
      float rinv = 1.f / sqrtf(ns + 1e-16f);
      #pragma unroll
      for (int i = 0; i < 9; ++i) out[(size_t)row*9 + i] = Qs[i]*rinv;
    }
  }
}

// ---------------- launcher ----------------
extern "C" void kernel_launch(void* const* d_in, const int* in_sizes, int n_in,
                              void* d_out, int out_size, void* d_ws, size_t ws_size,
                              hipStream_t stream) {
  const float* s = (const float*)d_in[0];
  const float* w = (const float*)d_in[1];
  const int B = in_sizes[0] / 9;
  char* ws = (char*)d_ws;
  f16*   wt    = (f16*)ws;
  float* biasp = (float*)(ws + 94208);
  float* out   = (float*)d_out;

  k0_prep<<<dim3(186), dim3(256), 0, stream>>>(
      (const float*)d_in[2],  (const float*)d_in[3],  (const float*)d_in[4],  (const float*)d_in[5],
      (const float*)d_in[6],  (const float*)d_in[7],  (const float*)d_in[8],  (const float*)d_in[9],
      (const float*)d_in[10], (const float*)d_in[11], (const float*)d_in[12], (const float*)d_in[13],
      wt, biasp);
  k_fused<<<dim3((B + 63) / 64), dim3(256), 0, stream>>>(wt, biasp, s, w, out, B);
}